// Round 10
// baseline (3192.642 us; speedup 1.0000x reference)
//
#include <hip/hip_runtime.h>
#include <math.h>

#define BATCH   8
#define NPTS    32768
#define FDIM    32
#define NGROUP  1024
#define GSIZE   32
#define KLANE   8       // per-lane candidate list length in KNN

// FPS: 8 blocks/batch x 512 thr x 8 pts/thr = 32768 (R13 geometry, proven
// register-resident: 56 VGPR).
#define NBLK    8
#define FTPB    512
#define CHUNK   (NPTS / NBLK)     // 4096 points per block
#define NFPSBLK (BATCH * NBLK)    // 64 producer blocks (first in grid)
#define KNNQPB  8                 // 8 queries (waves) per 512-thr knn block
#define NKNNBLK ((BATCH * NGROUP) / KNNQPB)   // 1024 consumer blocks

// Exact float32 distance in the reference's association: ((dx^2+dy^2)+dz^2),
// contraction blocked so bits match the numpy ref (argmax stability).
__device__ __forceinline__ float dist2f(float ax, float ay, float az,
                                        float bx, float by, float bz) {
  float dx = __fsub_rn(ax, bx);
  float dy = __fsub_rn(ay, by);
  float dz = __fsub_rn(az, bz);
  return __fadd_rn(__fadd_rn(__fmul_rn(dx, dx), __fmul_rn(dy, dy)),
                   __fmul_rn(dz, dz));
}

#define X8(M) M(0) M(1) M(2) M(3) M(4) M(5) M(6) M(7)

// ---------------------------------------------------------------------------
// R24 = R21 (all-RELAXED slots, best: 2417us) + SINGLE-BARRIER ALL-WAVE
// REDUNDANT CONSENSUS (B2 + LDS-bcast relay removed).
// Ledger: R13 acq/rel = 2872; R19 8-lines = 3225; R20 sc0 fenced = 3790;
//   R21 relaxed = 2417 (WIN: poll-fence removal); R22 sc0 dual = 2574
//   (scope closed); R23 spec coord prefetch = 2475 (null: coord load not
//   an exposed term -> consensus observe + barrier/relay dominate).
// R24 removes the relay: waves 1-7 no longer learn the winner second-hand
//   (wave0 observe -> LDS bcast -> B2 -> read, ~150-250cyc serial tail).
//   Instead ALL 64 lanes of EVERY wave poll slot[lane&7] (one 64B line,
//   coalesced), spin until own slot fresh, 3-round shfl_xor 8-max -> every
//   lane holds the winner directly. ONE __syncthreads per iteration.
// Safety (single barrier): a block's t+1 store needs its B1(t+1) which
//   needs all its waves past poll(t) -> no parity-(t&1) slot can be
//   overwritten (t+2 store) while any wave polls t (<=1-round-ahead
//   induction, same as 2-barrier). redv hazard closed: a wave's redv
//   write(t+1) is after its poll(t), which requires own wave0's redv
//   read(t) (own block's store is part of the poll condition).
// Poll traffic: 64 wave-streams/line vs 8 -- ~0.1 loads/cyc/line, trivial.
// Predicted: VGPR ~56; dur 2417 -> ~2150-2300; VALUBusy ~23-25%;
//   hbm_bytes flat (slots are cache-resident). Null (~2400) => relay was
//   hidden under observe RT; next lever = pipelined polls or floor.
// ---------------------------------------------------------------------------
__global__ __launch_bounds__(FTPB) void fused_kernel(
    const float* __restrict__ coord, const float* __restrict__ feat,
    const int* __restrict__ labels,
    unsigned long long* __restrict__ slots,   // [2][64] u64, pre-zeroed
    int* __restrict__ s_idx_ws,               // [8192] idx+1, pre-zeroed
    float* __restrict__ out) {
  __shared__ float redv[8];
  __shared__ int   redp[8];

  const int bx   = blockIdx.x;
  const int tid  = threadIdx.x;
  const int lane = tid & 63;
  const int wid  = tid >> 6;          // 0..7

  if (bx < NFPSBLK) {
    // ===================== FPS (producer) =====================
    const int b    = bx & 7;          // batch (XCD-local under %8 mapping)
    const int bk   = bx >> 3;         // block within batch
    const float* __restrict__ c = coord + (size_t)b * NPTS * 3;
    const float3* __restrict__ c3 = (const float3*)c;
    const int pbase = bk * CHUNK + tid;

#define DECL8(i) float x##i, y##i, z##i, d##i;
    X8(DECL8)
#undef DECL8

    // Init: distance to batch point 0; local argmax (ascending index +
    // strict > == np.argmax lowest-index tie-break).
    float qx = c[0], qy = c[1], qz = c[2];
    float bestv = -1.0f; int bestp = 0;
#define LOAD8(i) { int p = pbase + (i) * FTPB; float3 v = c3[p];            \
    x##i = v.x; y##i = v.y; z##i = v.z;                                      \
    float t2 = dist2f(v.x, v.y, v.z, qx, qy, qz); d##i = t2;                 \
    if (t2 > bestv) { bestv = t2; bestp = p; } }
    X8(LOAD8)
#undef LOAD8

    if (bk == 0 && tid == 0)
      __hip_atomic_store(&s_idx_ws[b * NGROUP + 0], 1, __ATOMIC_RELAXED,
                         __HIP_MEMORY_SCOPE_AGENT);   // idx 0, +1 encoding

    for (int t = 1; t < NGROUP; ++t) {
      // Wave-level argmax (max value, tie -> min index).
      float v = bestv; int p = bestp;
      #pragma unroll
      for (int m = 1; m < 64; m <<= 1) {
        float ov = __shfl_xor(v, m, 64);
        int   op = __shfl_xor(p, m, 64);
        if (ov > v || (ov == v && op < p)) { v = ov; p = op; }
      }
      if (lane == 0) { redv[wid] = v; redp[wid] = p; }
      __syncthreads();   // the ONLY barrier per iteration

      unsigned long long* base = slots + (size_t)(t & 1) * (BATCH * NBLK);
      if (wid == 0) {
        // Block-candidate reduce (wave0 only; sole consumer of redv/redp).
        float gv = redv[lane & 7]; int gp_ = redp[lane & 7];
        #pragma unroll
        for (int m = 1; m < 8; m <<= 1) {
          float ov = __shfl_xor(gv, m, 64);
          int   op = __shfl_xor(gp_, m, 64);
          if (ov > gv || (ov == gv && op < gp_)) { gv = ov; gp_ = op; }
        }
        if (lane == 0) {
          unsigned long long pk = ((unsigned long long)t << 47)
                                | ((unsigned long long)__float_as_uint(gv) << 15)
                                | (unsigned long long)(0x7FFF - gp_);
          __hip_atomic_store(base + (b << 3) + bk, pk, __ATOMIC_RELAXED,
                             __HIP_MEMORY_SCOPE_AGENT);
        }
      }

      // ALL waves poll all 8 slots directly (lane&7 -> one 64B line).
      const unsigned long long* sl = base + (b << 3) + (lane & 7);
      unsigned long long pk2;
      do {
        pk2 = __hip_atomic_load(sl, __ATOMIC_RELAXED,
                                __HIP_MEMORY_SCOPE_AGENT);
      } while ((int)(pk2 >> 47) != t);
      #pragma unroll
      for (int m = 1; m < 8; m <<= 1) {
        unsigned long long o = __shfl_xor(pk2, m, 64);
        if (o > pk2) pk2 = o;
      }

      const int gp = 0x7FFF - (int)(pk2 & 0x7FFF);
      if (bk == 0 && tid == 0)
        __hip_atomic_store(&s_idx_ws[b * NGROUP + t], gp + 1,
                           __ATOMIC_RELAXED, __HIP_MEMORY_SCOPE_AGENT);
      if (t == NGROUP - 1) break;

      float3 q = c3[gp];
      qx = q.x; qy = q.y; qz = q.z;
      bestv = -1.0f; bestp = 0;
#define UPD8(i) { float t2 = dist2f(x##i, y##i, z##i, qx, qy, qz);           \
    float nd = fminf(d##i, t2); d##i = nd;                                   \
    if (nd > bestv) { bestv = nd; bestp = pbase + (i) * FTPB; } }
      X8(UPD8)
#undef UPD8
    }
    return;
  }

  // ===================== KNN (consumer) =====================
  const int qid = (bx - NFPSBLK) * KNNQPB + wid;   // 0..8191
  const int b   = qid >> 10;
  const float* __restrict__ c = coord + (size_t)b * NPTS * 3;

  // Conservative backoff (~1/3 of estimated publish time in s_sleep(127)
  // chunks -- s_sleep counts CORE CLOCKS, R12 lesson), then slow spin.
  const int tq = qid & (NGROUP - 1);
  int enc = __hip_atomic_load(&s_idx_ws[qid], __ATOMIC_RELAXED,
                              __HIP_MEMORY_SCOPE_AGENT);
  for (int i = tq >> 2; i > 0 && enc == 0; --i) {
    __builtin_amdgcn_s_sleep(127);
    enc = __hip_atomic_load(&s_idx_ws[qid], __ATOMIC_RELAXED,
                            __HIP_MEMORY_SCOPE_AGENT);
  }
  while (enc == 0) {
    __builtin_amdgcn_s_sleep(64);
    enc = __hip_atomic_load(&s_idx_ws[qid], __ATOMIC_RELAXED,
                            __HIP_MEMORY_SCOPE_AGENT);
  }
  const int sp = __builtin_amdgcn_readfirstlane(enc - 1);
  const int gq = b * NPTS + sp;
  const float qx = coord[(size_t)gq * 3 + 0];
  const float qy = coord[(size_t)gq * 3 + 1];
  const float qz = coord[(size_t)gq * 3 + 2];

  // Per-lane ascending top-8 (value, index), static indexing only.
  float lv[KLANE]; int li[KLANE];
  #pragma unroll
  for (int j = 0; j < KLANE; ++j) { lv[j] = 1e30f; li[j] = 0x7fffffff; }

  // Branchless sorted insert; strict < keeps equal-distance earlier (lower)
  // indices first, matching lax.top_k tie order.
#define INSERT(D2, P) \
  if ((D2) < lv[KLANE - 1]) { \
    _Pragma("unroll") \
    for (int j = KLANE - 1; j >= 1; --j) { \
      bool up = (D2) < lv[j - 1]; \
      float nv = up ? lv[j - 1] : (((D2) < lv[j]) ? (D2) : lv[j]); \
      int   ni = up ? li[j - 1] : (((D2) < lv[j]) ? (P)  : li[j]); \
      lv[j] = nv; li[j] = ni; \
    } \
    if ((D2) < lv[0]) { lv[0] = (D2); li[0] = (P); } \
  }

  for (int s = 0; s < NPTS / 256; ++s) {   // 128 iterations, 4 pts/lane
    int p = (s << 8) | (lane << 2);
    const float4* c4 = (const float4*)(c + (size_t)p * 3);
    float4 f0 = c4[0], f1 = c4[1], f2 = c4[2];
    float dA = dist2f(f0.x, f0.y, f0.z, qx, qy, qz);
    float dB = dist2f(f0.w, f1.x, f1.y, qx, qy, qz);
    float dC = dist2f(f1.z, f1.w, f2.x, qx, qy, qz);
    float dD = dist2f(f2.y, f2.z, f2.w, qx, qy, qz);
    INSERT(dA, p);
    INSERT(dB, p + 1);
    INSERT(dC, p + 2);
    INSERT(dD, p + 3);
  }
#undef INSERT

  // Extract the 32 globally smallest (ascending, tie -> lower index).
  // Round 0 is the query itself (d2 == 0), excluded from the angle mean
  // like angles[:, :, 1:].
  int nbp = 0;
  for (int r = 0; r < GSIZE; ++r) {
    float mv = lv[0]; int mp = li[0];
    #pragma unroll
    for (int m = 1; m < 64; m <<= 1) {
      float ov = __shfl_xor(mv, m, 64);
      int   op = __shfl_xor(mp, m, 64);
      if (ov < mv || (ov == mv && op < mp)) { mv = ov; mp = op; }
    }
    if (lane == r) nbp = mp;
    if (lv[0] == mv && li[0] == mp) {  // unique winner pops its head
      #pragma unroll
      for (int j = 0; j < KLANE - 1; ++j) { lv[j] = lv[j + 1]; li[j] = li[j + 1]; }
      lv[KLANE - 1] = 1e30f; li[KLANE - 1] = 0x7fffffff;
    }
  }

  // Angle for lanes 1..31: theta = 2*atan2(||a*|b| - |a|*b||, ||a*|b| + |a|*b||)
  const float* aRow = feat + (size_t)gq * FDIM;
  float my_a = (lane < FDIM) ? aRow[lane] : 0.0f;

  float ang = 0.0f;
  if (lane >= 1 && lane < GSIZE) {
    const float4* a4 = (const float4*)aRow;
    const float4* b4 = (const float4*)(feat + ((size_t)b * NPTS + nbp) * FDIM);
    float4 av[FDIM / 4], bv[FDIM / 4];
    float aa = 0.0f, bb = 0.0f;
    #pragma unroll
    for (int k = 0; k < FDIM / 4; ++k) {
      av[k] = a4[k]; bv[k] = b4[k];
      aa += av[k].x * av[k].x + av[k].y * av[k].y + av[k].z * av[k].z + av[k].w * av[k].w;
      bb += bv[k].x * bv[k].x + bv[k].y * bv[k].y + bv[k].z * bv[k].z + bv[k].w * bv[k].w;
    }
    float an = sqrtf(aa), bn = sqrtf(bb);
    float num2 = 0.0f, den2 = 0.0f;
    #pragma unroll
    for (int k = 0; k < FDIM / 4; ++k) {
      float n0 = av[k].x * bn - an * bv[k].x, dd0 = av[k].x * bn + an * bv[k].x;
      float n1 = av[k].y * bn - an * bv[k].y, dd1 = av[k].y * bn + an * bv[k].y;
      float n2 = av[k].z * bn - an * bv[k].z, dd2 = av[k].z * bn + an * bv[k].z;
      float n3 = av[k].w * bn - an * bv[k].w, dd3 = av[k].w * bn + an * bv[k].w;
      num2 += n0 * n0 + n1 * n1 + n2 * n2 + n3 * n3;
      den2 += dd0 * dd0 + dd1 * dd1 + dd2 * dd2 + dd3 * dd3;
    }
    ang = 2.0f * atan2f(sqrtf(num2), sqrtf(den2));
  }

  // Wave sum of the 31 angles -> p_curv everywhere.
  float tot = ang;
  #pragma unroll
  for (int m = 1; m < 64; m <<= 1) tot += __shfl_xor(tot, m, 64);
  float p_curv = tot / 31.0f;

  // Outputs (flat concatenation, all as float32).
  float* out_xyz  = out;                              // 8192*3
  float* out_feat = out + (size_t)BATCH * NGROUP * 3; // 8192*33
  float* out_sw   = out_feat + (size_t)BATCH * NGROUP * (FDIM + 1);
  float* out_lab  = out_sw  + (size_t)BATCH * NGROUP;
  float* out_sif  = out_lab + (size_t)BATCH * NGROUP;

  if (lane < FDIM)  out_feat[(size_t)qid * (FDIM + 1) + lane] = my_a;
  if (lane == FDIM) out_feat[(size_t)qid * (FDIM + 1) + FDIM] = p_curv;
  if (lane == 0) {
    out_xyz[(size_t)qid * 3 + 0] = qx;
    out_xyz[(size_t)qid * 3 + 1] = qy;
    out_xyz[(size_t)qid * 3 + 2] = qz;
    out_sw[qid]  = (p_curv > 0.087266f) ? 1.0f : 0.0f;
    out_lab[qid] = (float)labels[gq];
    out_sif[qid] = (float)gq;   // s_idx + b*N
  }
}

extern "C" void kernel_launch(void* const* d_in, const int* in_sizes, int n_in,
                              void* d_out, int out_size, void* d_ws, size_t ws_size,
                              hipStream_t stream) {
  const float* coord  = (const float*)d_in[0];
  const float* feat   = (const float*)d_in[1];
  const int*   labels = (const int*)d_in[2];

  // ws layout: [2][64] u64 ping-pong slots, then [8192] int s_idx (+1
  // encoded, 0 = unpublished). Both must start zeroed.
  unsigned long long* slots = (unsigned long long*)d_ws;
  int* s_idx_ws = (int*)((char*)d_ws +
                         2 * BATCH * NBLK * sizeof(unsigned long long));
  const size_t zbytes = 2 * BATCH * NBLK * sizeof(unsigned long long)
                      + (size_t)BATCH * NGROUP * sizeof(int);

  hipMemsetAsync(d_ws, 0, zbytes, stream);
  fused_kernel<<<NFPSBLK + NKNNBLK, FTPB, 0, stream>>>(
      coord, feat, labels, slots, s_idx_ws, (float*)d_out);
}

// Round 11
// 2417.719 us; speedup vs baseline: 1.3205x; 1.3205x over previous
//
#include <hip/hip_runtime.h>
#include <math.h>

#define BATCH   8
#define NPTS    32768
#define FDIM    32
#define NGROUP  1024
#define GSIZE   32
#define KLANE   8       // per-lane candidate list length in KNN

// FPS: 8 blocks/batch x 512 thr x 8 pts/thr = 32768 (R13 geometry, proven
// register-resident: 56 VGPR).
#define NBLK    8
#define FTPB    512
#define CHUNK   (NPTS / NBLK)     // 4096 points per block
#define NFPSBLK (BATCH * NBLK)    // 64 producer blocks (first in grid)
#define KNNQPB  8                 // 8 queries (waves) per 512-thr knn block
#define NKNNBLK ((BATCH * NGROUP) / KNNQPB)   // 1024 consumer blocks

// Exact float32 distance in the reference's association: ((dx^2+dy^2)+dz^2),
// contraction blocked so bits match the numpy ref (argmax stability).
__device__ __forceinline__ float dist2f(float ax, float ay, float az,
                                        float bx, float by, float bz) {
  float dx = __fsub_rn(ax, bx);
  float dy = __fsub_rn(ay, by);
  float dz = __fsub_rn(az, bz);
  return __fadd_rn(__fadd_rn(__fmul_rn(dx, dx), __fmul_rn(dy, dy)),
                   __fmul_rn(dz, dz));
}

#define X8(M) M(0) M(1) M(2) M(3) M(4) M(5) M(6) M(7)

#define SLOT_LD(p) __hip_atomic_load((p), __ATOMIC_RELAXED, \
                                     __HIP_MEMORY_SCOPE_AGENT)

// ---------------------------------------------------------------------------
// R25 = R21 (all-RELAXED, shared line, wid0 polls, LDS relay; best: 2417us)
// + 4-DEEP ROTATING PIPELINED POLL.
// Ledger: R13 acq/rel=2872; R19 8-lines=3225; R20 sc0 fenced dual=3790;
//   R21 relaxed=2417 (WIN); R22 sc0 relaxed dual=2574; R23 spec-coord=2475
//   (null); R24 all-wave redundant poll=3127 (8x poll streams queue at the
//   MALL bank and slow the store itself -- minimal-traffic shape is right).
// R21 residual observe ~900cyc = propagation (~300) + DISCOVERY DELAY +
//   straggler. R21's poll samples memory once per RT (issue, full vmcnt
//   wait, compare, reissue): avg discovery ~1.5xRT after arrival. R25 keeps
//   4 independent relaxed loads in flight per polling lane (rotating
//   check-oldest-reissue; s_sleep(2)~128cyc staggered prime) -> sampling
//   cadence ~RT/4, discovery ~RT/2+RT/8. No new lines/writers/protocol;
//   traffic 4 streams per lane from wid0's 8 lanes only (not R24's 512).
//   Monotonic tag makes stale reads harmless; atomics can't be merged.
// Predicted: VGPR 56->64-72; dur 2417 -> ~2100-2250; VALUBusy 22-24%.
// Null (~2400) => cadence not the limiter; all consensus axes (protocol,
// layout, scope, ordering, relay, cadence) then measured-closed -> floor.
// ---------------------------------------------------------------------------
__global__ __launch_bounds__(FTPB) void fused_kernel(
    const float* __restrict__ coord, const float* __restrict__ feat,
    const int* __restrict__ labels,
    unsigned long long* __restrict__ slots,   // [2][64] u64, pre-zeroed
    int* __restrict__ s_idx_ws,               // [8192] idx+1, pre-zeroed
    float* __restrict__ out) {
  __shared__ float redv[8];
  __shared__ int   redp[8];
  __shared__ unsigned long long bcast;

  const int bx   = blockIdx.x;
  const int tid  = threadIdx.x;
  const int lane = tid & 63;
  const int wid  = tid >> 6;          // 0..7

  if (bx < NFPSBLK) {
    // ===================== FPS (producer) =====================
    const int b    = bx & 7;          // batch (XCD-local under %8 mapping)
    const int bk   = bx >> 3;         // block within batch
    const float* __restrict__ c = coord + (size_t)b * NPTS * 3;
    const float3* __restrict__ c3 = (const float3*)c;
    const int pbase = bk * CHUNK + tid;

#define DECL8(i) float x##i, y##i, z##i, d##i;
    X8(DECL8)
#undef DECL8

    // Init: distance to batch point 0; local argmax (ascending index +
    // strict > == np.argmax lowest-index tie-break).
    float qx = c[0], qy = c[1], qz = c[2];
    float bestv = -1.0f; int bestp = 0;
#define LOAD8(i) { int p = pbase + (i) * FTPB; float3 v = c3[p];            \
    x##i = v.x; y##i = v.y; z##i = v.z;                                      \
    float t2 = dist2f(v.x, v.y, v.z, qx, qy, qz); d##i = t2;                 \
    if (t2 > bestv) { bestv = t2; bestp = p; } }
    X8(LOAD8)
#undef LOAD8

    if (bk == 0 && tid == 0)
      __hip_atomic_store(&s_idx_ws[b * NGROUP + 0], 1, __ATOMIC_RELAXED,
                         __HIP_MEMORY_SCOPE_AGENT);   // idx 0, +1 encoding

    for (int t = 1; t < NGROUP; ++t) {
      // Wave-level argmax (max value, tie -> min index).
      float v = bestv; int p = bestp;
      #pragma unroll
      for (int m = 1; m < 64; m <<= 1) {
        float ov = __shfl_xor(v, m, 64);
        int   op = __shfl_xor(p, m, 64);
        if (ov > v || (ov == v && op < p)) { v = ov; p = op; }
      }
      if (lane == 0) { redv[wid] = v; redp[wid] = p; }
      __syncthreads();   // B1

      if (wid == 0) {
        float gv = redv[lane & 7]; int gp_ = redp[lane & 7];
        #pragma unroll
        for (int m = 1; m < 8; m <<= 1) {
          float ov = __shfl_xor(gv, m, 64);
          int   op = __shfl_xor(gp_, m, 64);
          if (ov > gv || (ov == gv && op < gp_)) { gv = ov; gp_ = op; }
        }
        unsigned long long* base = slots + (size_t)(t & 1) * (BATCH * NBLK);
        if (lane == 0) {
          unsigned long long pk = ((unsigned long long)t << 47)
                                | ((unsigned long long)__float_as_uint(gv) << 15)
                                | (unsigned long long)(0x7FFF - gp_);
          __hip_atomic_store(base + (b << 3) + bk, pk, __ATOMIC_RELAXED,
                             __HIP_MEMORY_SCOPE_AGENT);
        }
        unsigned long long pk2 = 0;
        if (lane < 8) {
          const unsigned long long* sl = base + (b << 3) + lane;
          // 4-deep rotating pipelined poll: ~RT/4 sampling cadence.
          unsigned long long a0, a1, a2, a3;
          a0 = SLOT_LD(sl); __builtin_amdgcn_s_sleep(2);
          a1 = SLOT_LD(sl); __builtin_amdgcn_s_sleep(2);
          a2 = SLOT_LD(sl); __builtin_amdgcn_s_sleep(2);
          a3 = SLOT_LD(sl);
          for (;;) {
            if ((int)(a0 >> 47) == t) { pk2 = a0; break; }
            a0 = SLOT_LD(sl);
            if ((int)(a1 >> 47) == t) { pk2 = a1; break; }
            a1 = SLOT_LD(sl);
            if ((int)(a2 >> 47) == t) { pk2 = a2; break; }
            a2 = SLOT_LD(sl);
            if ((int)(a3 >> 47) == t) { pk2 = a3; break; }
            a3 = SLOT_LD(sl);
          }
        }
        #pragma unroll
        for (int m = 1; m < 8; m <<= 1) {
          unsigned long long o = __shfl_xor(pk2, m, 64);
          if (o > pk2) pk2 = o;
        }
        if (lane == 0) bcast = pk2;
      }
      __syncthreads();   // B2

      const unsigned long long wpk = bcast;
      const int gp = 0x7FFF - (int)(wpk & 0x7FFF);
      if (bk == 0 && tid == 0)
        __hip_atomic_store(&s_idx_ws[b * NGROUP + t], gp + 1,
                           __ATOMIC_RELAXED, __HIP_MEMORY_SCOPE_AGENT);
      if (t == NGROUP - 1) break;

      float3 q = c3[gp];
      qx = q.x; qy = q.y; qz = q.z;
      bestv = -1.0f; bestp = 0;
#define UPD8(i) { float t2 = dist2f(x##i, y##i, z##i, qx, qy, qz);           \
    float nd = fminf(d##i, t2); d##i = nd;                                   \
    if (nd > bestv) { bestv = nd; bestp = pbase + (i) * FTPB; } }
      X8(UPD8)
#undef UPD8
    }
    return;
  }

  // ===================== KNN (consumer) =====================
  const int qid = (bx - NFPSBLK) * KNNQPB + wid;   // 0..8191
  const int b   = qid >> 10;
  const float* __restrict__ c = coord + (size_t)b * NPTS * 3;

  // Conservative backoff (~1/3 of estimated publish time in s_sleep(127)
  // chunks -- s_sleep counts CORE CLOCKS, R12 lesson), then slow spin.
  const int tq = qid & (NGROUP - 1);
  int enc = __hip_atomic_load(&s_idx_ws[qid], __ATOMIC_RELAXED,
                              __HIP_MEMORY_SCOPE_AGENT);
  for (int i = tq >> 2; i > 0 && enc == 0; --i) {
    __builtin_amdgcn_s_sleep(127);
    enc = __hip_atomic_load(&s_idx_ws[qid], __ATOMIC_RELAXED,
                            __HIP_MEMORY_SCOPE_AGENT);
  }
  while (enc == 0) {
    __builtin_amdgcn_s_sleep(64);
    enc = __hip_atomic_load(&s_idx_ws[qid], __ATOMIC_RELAXED,
                            __HIP_MEMORY_SCOPE_AGENT);
  }
  const int sp = __builtin_amdgcn_readfirstlane(enc - 1);
  const int gq = b * NPTS + sp;
  const float qx = coord[(size_t)gq * 3 + 0];
  const float qy = coord[(size_t)gq * 3 + 1];
  const float qz = coord[(size_t)gq * 3 + 2];

  // Per-lane ascending top-8 (value, index), static indexing only.
  float lv[KLANE]; int li[KLANE];
  #pragma unroll
  for (int j = 0; j < KLANE; ++j) { lv[j] = 1e30f; li[j] = 0x7fffffff; }

  // Branchless sorted insert; strict < keeps equal-distance earlier (lower)
  // indices first, matching lax.top_k tie order.
#define INSERT(D2, P) \
  if ((D2) < lv[KLANE - 1]) { \
    _Pragma("unroll") \
    for (int j = KLANE - 1; j >= 1; --j) { \
      bool up = (D2) < lv[j - 1]; \
      float nv = up ? lv[j - 1] : (((D2) < lv[j]) ? (D2) : lv[j]); \
      int   ni = up ? li[j - 1] : (((D2) < lv[j]) ? (P)  : li[j]); \
      lv[j] = nv; li[j] = ni; \
    } \
    if ((D2) < lv[0]) { lv[0] = (D2); li[0] = (P); } \
  }

  for (int s = 0; s < NPTS / 256; ++s) {   // 128 iterations, 4 pts/lane
    int p = (s << 8) | (lane << 2);
    const float4* c4 = (const float4*)(c + (size_t)p * 3);
    float4 f0 = c4[0], f1 = c4[1], f2 = c4[2];
    float dA = dist2f(f0.x, f0.y, f0.z, qx, qy, qz);
    float dB = dist2f(f0.w, f1.x, f1.y, qx, qy, qz);
    float dC = dist2f(f1.z, f1.w, f2.x, qx, qy, qz);
    float dD = dist2f(f2.y, f2.z, f2.w, qx, qy, qz);
    INSERT(dA, p);
    INSERT(dB, p + 1);
    INSERT(dC, p + 2);
    INSERT(dD, p + 3);
  }
#undef INSERT

  // Extract the 32 globally smallest (ascending, tie -> lower index).
  // Round 0 is the query itself (d2 == 0), excluded from the angle mean
  // like angles[:, :, 1:].
  int nbp = 0;
  for (int r = 0; r < GSIZE; ++r) {
    float mv = lv[0]; int mp = li[0];
    #pragma unroll
    for (int m = 1; m < 64; m <<= 1) {
      float ov = __shfl_xor(mv, m, 64);
      int   op = __shfl_xor(mp, m, 64);
      if (ov < mv || (ov == mv && op < mp)) { mv = ov; mp = op; }
    }
    if (lane == r) nbp = mp;
    if (lv[0] == mv && li[0] == mp) {  // unique winner pops its head
      #pragma unroll
      for (int j = 0; j < KLANE - 1; ++j) { lv[j] = lv[j + 1]; li[j] = li[j + 1]; }
      lv[KLANE - 1] = 1e30f; li[KLANE - 1] = 0x7fffffff;
    }
  }

  // Angle for lanes 1..31: theta = 2*atan2(||a*|b| - |a|*b||, ||a*|b| + |a|*b||)
  const float* aRow = feat + (size_t)gq * FDIM;
  float my_a = (lane < FDIM) ? aRow[lane] : 0.0f;

  float ang = 0.0f;
  if (lane >= 1 && lane < GSIZE) {
    const float4* a4 = (const float4*)aRow;
    const float4* b4 = (const float4*)(feat + ((size_t)b * NPTS + nbp) * FDIM);
    float4 av[FDIM / 4], bv[FDIM / 4];
    float aa = 0.0f, bb = 0.0f;
    #pragma unroll
    for (int k = 0; k < FDIM / 4; ++k) {
      av[k] = a4[k]; bv[k] = b4[k];
      aa += av[k].x * av[k].x + av[k].y * av[k].y + av[k].z * av[k].z + av[k].w * av[k].w;
      bb += bv[k].x * bv[k].x + bv[k].y * bv[k].y + bv[k].z * bv[k].z + bv[k].w * bv[k].w;
    }
    float an = sqrtf(aa), bn = sqrtf(bb);
    float num2 = 0.0f, den2 = 0.0f;
    #pragma unroll
    for (int k = 0; k < FDIM / 4; ++k) {
      float n0 = av[k].x * bn - an * bv[k].x, dd0 = av[k].x * bn + an * bv[k].x;
      float n1 = av[k].y * bn - an * bv[k].y, dd1 = av[k].y * bn + an * bv[k].y;
      float n2 = av[k].z * bn - an * bv[k].z, dd2 = av[k].z * bn + an * bv[k].z;
      float n3 = av[k].w * bn - an * bv[k].w, dd3 = av[k].w * bn + an * bv[k].w;
      num2 += n0 * n0 + n1 * n1 + n2 * n2 + n3 * n3;
      den2 += dd0 * dd0 + dd1 * dd1 + dd2 * dd2 + dd3 * dd3;
    }
    ang = 2.0f * atan2f(sqrtf(num2), sqrtf(den2));
  }

  // Wave sum of the 31 angles -> p_curv everywhere.
  float tot = ang;
  #pragma unroll
  for (int m = 1; m < 64; m <<= 1) tot += __shfl_xor(tot, m, 64);
  float p_curv = tot / 31.0f;

  // Outputs (flat concatenation, all as float32).
  float* out_xyz  = out;                              // 8192*3
  float* out_feat = out + (size_t)BATCH * NGROUP * 3; // 8192*33
  float* out_sw   = out_feat + (size_t)BATCH * NGROUP * (FDIM + 1);
  float* out_lab  = out_sw  + (size_t)BATCH * NGROUP;
  float* out_sif  = out_lab + (size_t)BATCH * NGROUP;

  if (lane < FDIM)  out_feat[(size_t)qid * (FDIM + 1) + lane] = my_a;
  if (lane == FDIM) out_feat[(size_t)qid * (FDIM + 1) + FDIM] = p_curv;
  if (lane == 0) {
    out_xyz[(size_t)qid * 3 + 0] = qx;
    out_xyz[(size_t)qid * 3 + 1] = qy;
    out_xyz[(size_t)qid * 3 + 2] = qz;
    out_sw[qid]  = (p_curv > 0.087266f) ? 1.0f : 0.0f;
    out_lab[qid] = (float)labels[gq];
    out_sif[qid] = (float)gq;   // s_idx + b*N
  }
}

extern "C" void kernel_launch(void* const* d_in, const int* in_sizes, int n_in,
                              void* d_out, int out_size, void* d_ws, size_t ws_size,
                              hipStream_t stream) {
  const float* coord  = (const float*)d_in[0];
  const float* feat   = (const float*)d_in[1];
  const int*   labels = (const int*)d_in[2];

  // ws layout: [2][64] u64 ping-pong slots, then [8192] int s_idx (+1
  // encoded, 0 = unpublished). Both must start zeroed.
  unsigned long long* slots = (unsigned long long*)d_ws;
  int* s_idx_ws = (int*)((char*)d_ws +
                         2 * BATCH * NBLK * sizeof(unsigned long long));
  const size_t zbytes = 2 * BATCH * NBLK * sizeof(unsigned long long)
                      + (size_t)BATCH * NGROUP * sizeof(int);

  hipMemsetAsync(d_ws, 0, zbytes, stream);
  fused_kernel<<<NFPSBLK + NKNNBLK, FTPB, 0, stream>>>(
      coord, feat, labels, slots, s_idx_ws, (float*)d_out);
}

// Round 12
// 2414.291 us; speedup vs baseline: 1.3224x; 1.0014x over previous
//
#include <hip/hip_runtime.h>
#include <math.h>

#define BATCH   8
#define NPTS    32768
#define FDIM    32
#define NGROUP  1024
#define GSIZE   32
#define KLANE   8       // per-lane candidate list length in KNN

// FPS: 8 blocks/batch x 512 thr x 8 pts/thr = 32768 (R13 geometry, proven
// register-resident: 56 VGPR).
#define NBLK    8
#define FTPB    512
#define CHUNK   (NPTS / NBLK)     // 4096 points per block
#define NFPSBLK (BATCH * NBLK)    // 64 producer blocks (first in grid)
#define KNNQPB  8                 // 8 queries (waves) per 512-thr knn block
#define NKNNBLK ((BATCH * NGROUP) / KNNQPB)   // 1024 consumer blocks

// Exact float32 distance in the reference's association: ((dx^2+dy^2)+dz^2),
// contraction blocked so bits match the numpy ref (argmax stability).
__device__ __forceinline__ float dist2f(float ax, float ay, float az,
                                        float bx, float by, float bz) {
  float dx = __fsub_rn(ax, bx);
  float dy = __fsub_rn(ay, by);
  float dz = __fsub_rn(az, bz);
  return __fadd_rn(__fadd_rn(__fmul_rn(dx, dx), __fmul_rn(dy, dy)),
                   __fmul_rn(dz, dz));
}

#define X8(M) M(0) M(1) M(2) M(3) M(4) M(5) M(6) M(7)

#define SLOT_LD(p) __hip_atomic_load((p), __ATOMIC_RELAXED, \
                                     __HIP_MEMORY_SCOPE_AGENT)

// ---------------------------------------------------------------------------
// R26 = R25 (equal-best, 2395-2417us) + CONSUMER-BACKOFF HEATER.
// Consensus axes ALL measured-closed: protocol (R6-R14 prior session),
//   layout (R19: 8 lines=3225), writer count (R15-18 void/structural),
//   scope (R20=3790, R22=2574), ORDERING (R21=2417, the win: relaxed
//   removed per-poll acquire fences), relay (R24: all-wave poll=3127),
//   cadence (R25: 4-deep pipelined poll = null).
// Untested axis: THE CLOCK. Cycle arithmetic only balances at sclk~1GHz
//   (R21's saving = ~445cyc/iter at 1GHz ~ 2-4 polls x ~100-150cyc fence;
//   implausible at 2.4GHz). VALUBusy 22%, 7000+ waves s_sleeping -> DPM
//   activity monitor sees a near-idle chip and parks sclk low. ~60% of the
//   2.36us period is compute that scales with sclk.
// R26: consumer BACKOFF chunks (they wait anyway) become {16-op dependent
//   v_fma chain (~64cyc, 0.25 IPC -> low issue-slot pressure, co-resident
//   producer waves keep their slots) + s_sleep(1)} x 64 -- same wall-time
//   budget as the old s_sleep(127) chunk, ~50% VALU duty, zero extra memory
//   traffic. Final acquisition spin unchanged. Producers untouched.
// Predicted: VALUBusy 22 -> 45-70% (verifies mechanism); clock theory right
//   -> dur ~1550-1900. Issue-stealing -> 2500-2900 (revert+floor). Null at
//   high VALUBusy -> clock already maxed -> declare floor.
// ---------------------------------------------------------------------------
__global__ __launch_bounds__(FTPB) void fused_kernel(
    const float* __restrict__ coord, const float* __restrict__ feat,
    const int* __restrict__ labels,
    unsigned long long* __restrict__ slots,   // [2][64] u64, pre-zeroed
    int* __restrict__ s_idx_ws,               // [8192] idx+1, pre-zeroed
    float* __restrict__ out) {
  __shared__ float redv[8];
  __shared__ int   redp[8];
  __shared__ unsigned long long bcast;

  const int bx   = blockIdx.x;
  const int tid  = threadIdx.x;
  const int lane = tid & 63;
  const int wid  = tid >> 6;          // 0..7

  if (bx < NFPSBLK) {
    // ===================== FPS (producer) =====================
    const int b    = bx & 7;          // batch (XCD-local under %8 mapping)
    const int bk   = bx >> 3;         // block within batch
    const float* __restrict__ c = coord + (size_t)b * NPTS * 3;
    const float3* __restrict__ c3 = (const float3*)c;
    const int pbase = bk * CHUNK + tid;

#define DECL8(i) float x##i, y##i, z##i, d##i;
    X8(DECL8)
#undef DECL8

    // Init: distance to batch point 0; local argmax (ascending index +
    // strict > == np.argmax lowest-index tie-break).
    float qx = c[0], qy = c[1], qz = c[2];
    float bestv = -1.0f; int bestp = 0;
#define LOAD8(i) { int p = pbase + (i) * FTPB; float3 v = c3[p];            \
    x##i = v.x; y##i = v.y; z##i = v.z;                                      \
    float t2 = dist2f(v.x, v.y, v.z, qx, qy, qz); d##i = t2;                 \
    if (t2 > bestv) { bestv = t2; bestp = p; } }
    X8(LOAD8)
#undef LOAD8

    if (bk == 0 && tid == 0)
      __hip_atomic_store(&s_idx_ws[b * NGROUP + 0], 1, __ATOMIC_RELAXED,
                         __HIP_MEMORY_SCOPE_AGENT);   // idx 0, +1 encoding

    for (int t = 1; t < NGROUP; ++t) {
      // Wave-level argmax (max value, tie -> min index).
      float v = bestv; int p = bestp;
      #pragma unroll
      for (int m = 1; m < 64; m <<= 1) {
        float ov = __shfl_xor(v, m, 64);
        int   op = __shfl_xor(p, m, 64);
        if (ov > v || (ov == v && op < p)) { v = ov; p = op; }
      }
      if (lane == 0) { redv[wid] = v; redp[wid] = p; }
      __syncthreads();   // B1

      if (wid == 0) {
        float gv = redv[lane & 7]; int gp_ = redp[lane & 7];
        #pragma unroll
        for (int m = 1; m < 8; m <<= 1) {
          float ov = __shfl_xor(gv, m, 64);
          int   op = __shfl_xor(gp_, m, 64);
          if (ov > gv || (ov == gv && op < gp_)) { gv = ov; gp_ = op; }
        }
        unsigned long long* base = slots + (size_t)(t & 1) * (BATCH * NBLK);
        if (lane == 0) {
          unsigned long long pk = ((unsigned long long)t << 47)
                                | ((unsigned long long)__float_as_uint(gv) << 15)
                                | (unsigned long long)(0x7FFF - gp_);
          __hip_atomic_store(base + (b << 3) + bk, pk, __ATOMIC_RELAXED,
                             __HIP_MEMORY_SCOPE_AGENT);
        }
        unsigned long long pk2 = 0;
        if (lane < 8) {
          const unsigned long long* sl = base + (b << 3) + lane;
          // 4-deep rotating pipelined poll (R25; equal-best, kept).
          unsigned long long a0, a1, a2, a3;
          a0 = SLOT_LD(sl); __builtin_amdgcn_s_sleep(2);
          a1 = SLOT_LD(sl); __builtin_amdgcn_s_sleep(2);
          a2 = SLOT_LD(sl); __builtin_amdgcn_s_sleep(2);
          a3 = SLOT_LD(sl);
          for (;;) {
            if ((int)(a0 >> 47) == t) { pk2 = a0; break; }
            a0 = SLOT_LD(sl);
            if ((int)(a1 >> 47) == t) { pk2 = a1; break; }
            a1 = SLOT_LD(sl);
            if ((int)(a2 >> 47) == t) { pk2 = a2; break; }
            a2 = SLOT_LD(sl);
            if ((int)(a3 >> 47) == t) { pk2 = a3; break; }
            a3 = SLOT_LD(sl);
          }
        }
        #pragma unroll
        for (int m = 1; m < 8; m <<= 1) {
          unsigned long long o = __shfl_xor(pk2, m, 64);
          if (o > pk2) pk2 = o;
        }
        if (lane == 0) bcast = pk2;
      }
      __syncthreads();   // B2

      const unsigned long long wpk = bcast;
      const int gp = 0x7FFF - (int)(wpk & 0x7FFF);
      if (bk == 0 && tid == 0)
        __hip_atomic_store(&s_idx_ws[b * NGROUP + t], gp + 1,
                           __ATOMIC_RELAXED, __HIP_MEMORY_SCOPE_AGENT);
      if (t == NGROUP - 1) break;

      float3 q = c3[gp];
      qx = q.x; qy = q.y; qz = q.z;
      bestv = -1.0f; bestp = 0;
#define UPD8(i) { float t2 = dist2f(x##i, y##i, z##i, qx, qy, qz);           \
    float nd = fminf(d##i, t2); d##i = nd;                                   \
    if (nd > bestv) { bestv = nd; bestp = pbase + (i) * FTPB; } }
      X8(UPD8)
#undef UPD8
    }
    return;
  }

  // ===================== KNN (consumer) =====================
  const int qid = (bx - NFPSBLK) * KNNQPB + wid;   // 0..8191
  const int b   = qid >> 10;
  const float* __restrict__ c = coord + (size_t)b * NPTS * 3;

  // HEATER backoff (R26): same wall-time budget as the old s_sleep(127)
  // chunks (~8k clk, tq>>2 chunks), but each chunk is 64 x {16-op
  // dependent v_fma chain + s_sleep(1)} -- ~50% VALU duty raises the DPM
  // activity metric so sclk holds a boost state, while the dependent chain
  // (0.25 IPC) leaves issue slots for co-resident producer waves. One
  // s_idx load per chunk (unchanged memory cadence). Values unused.
  const int tq = qid & (NGROUP - 1);
  int enc = __hip_atomic_load(&s_idx_ws[qid], __ATOMIC_RELAXED,
                              __HIP_MEMORY_SCOPE_AGENT);
  float h0 = 1.0f + (float)(lane & 7) * 0.125f, h1 = 1.000001f;
  for (int i = tq >> 2; i > 0 && enc == 0; --i) {
    #pragma unroll 1
    for (int r = 0; r < 64; ++r) {
      #pragma unroll
      for (int j = 0; j < 8; ++j) {
        h0 = __builtin_fmaf(h0, h1, 0.5f);
        h1 = __builtin_fmaf(h1, h0, -0.25f);
      }
      __builtin_amdgcn_s_sleep(1);
    }
    enc = __hip_atomic_load(&s_idx_ws[qid], __ATOMIC_RELAXED,
                            __HIP_MEMORY_SCOPE_AGENT);
  }
  asm volatile("" :: "v"(h0), "v"(h1));   // keep heater chain live
  while (enc == 0) {
    __builtin_amdgcn_s_sleep(64);
    enc = __hip_atomic_load(&s_idx_ws[qid], __ATOMIC_RELAXED,
                            __HIP_MEMORY_SCOPE_AGENT);
  }
  const int sp = __builtin_amdgcn_readfirstlane(enc - 1);
  const int gq = b * NPTS + sp;
  const float qx = coord[(size_t)gq * 3 + 0];
  const float qy = coord[(size_t)gq * 3 + 1];
  const float qz = coord[(size_t)gq * 3 + 2];

  // Per-lane ascending top-8 (value, index), static indexing only.
  float lv[KLANE]; int li[KLANE];
  #pragma unroll
  for (int j = 0; j < KLANE; ++j) { lv[j] = 1e30f; li[j] = 0x7fffffff; }

  // Branchless sorted insert; strict < keeps equal-distance earlier (lower)
  // indices first, matching lax.top_k tie order.
#define INSERT(D2, P) \
  if ((D2) < lv[KLANE - 1]) { \
    _Pragma("unroll") \
    for (int j = KLANE - 1; j >= 1; --j) { \
      bool up = (D2) < lv[j - 1]; \
      float nv = up ? lv[j - 1] : (((D2) < lv[j]) ? (D2) : lv[j]); \
      int   ni = up ? li[j - 1] : (((D2) < lv[j]) ? (P)  : li[j]); \
      lv[j] = nv; li[j] = ni; \
    } \
    if ((D2) < lv[0]) { lv[0] = (D2); li[0] = (P); } \
  }

  for (int s = 0; s < NPTS / 256; ++s) {   // 128 iterations, 4 pts/lane
    int p = (s << 8) | (lane << 2);
    const float4* c4 = (const float4*)(c + (size_t)p * 3);
    float4 f0 = c4[0], f1 = c4[1], f2 = c4[2];
    float dA = dist2f(f0.x, f0.y, f0.z, qx, qy, qz);
    float dB = dist2f(f0.w, f1.x, f1.y, qx, qy, qz);
    float dC = dist2f(f1.z, f1.w, f2.x, qx, qy, qz);
    float dD = dist2f(f2.y, f2.z, f2.w, qx, qy, qz);
    INSERT(dA, p);
    INSERT(dB, p + 1);
    INSERT(dC, p + 2);
    INSERT(dD, p + 3);
  }
#undef INSERT

  // Extract the 32 globally smallest (ascending, tie -> lower index).
  // Round 0 is the query itself (d2 == 0), excluded from the angle mean
  // like angles[:, :, 1:].
  int nbp = 0;
  for (int r = 0; r < GSIZE; ++r) {
    float mv = lv[0]; int mp = li[0];
    #pragma unroll
    for (int m = 1; m < 64; m <<= 1) {
      float ov = __shfl_xor(mv, m, 64);
      int   op = __shfl_xor(mp, m, 64);
      if (ov < mv || (ov == mv && op < mp)) { mv = ov; mp = op; }
    }
    if (lane == r) nbp = mp;
    if (lv[0] == mv && li[0] == mp) {  // unique winner pops its head
      #pragma unroll
      for (int j = 0; j < KLANE - 1; ++j) { lv[j] = lv[j + 1]; li[j] = li[j + 1]; }
      lv[KLANE - 1] = 1e30f; li[KLANE - 1] = 0x7fffffff;
    }
  }

  // Angle for lanes 1..31: theta = 2*atan2(||a*|b| - |a|*b||, ||a*|b| + |a|*b||)
  const float* aRow = feat + (size_t)gq * FDIM;
  float my_a = (lane < FDIM) ? aRow[lane] : 0.0f;

  float ang = 0.0f;
  if (lane >= 1 && lane < GSIZE) {
    const float4* a4 = (const float4*)aRow;
    const float4* b4 = (const float4*)(feat + ((size_t)b * NPTS + nbp) * FDIM);
    float4 av[FDIM / 4], bv[FDIM / 4];
    float aa = 0.0f, bb = 0.0f;
    #pragma unroll
    for (int k = 0; k < FDIM / 4; ++k) {
      av[k] = a4[k]; bv[k] = b4[k];
      aa += av[k].x * av[k].x + av[k].y * av[k].y + av[k].z * av[k].z + av[k].w * av[k].w;
      bb += bv[k].x * bv[k].x + bv[k].y * bv[k].y + bv[k].z * bv[k].z + bv[k].w * bv[k].w;
    }
    float an = sqrtf(aa), bn = sqrtf(bb);
    float num2 = 0.0f, den2 = 0.0f;
    #pragma unroll
    for (int k = 0; k < FDIM / 4; ++k) {
      float n0 = av[k].x * bn - an * bv[k].x, dd0 = av[k].x * bn + an * bv[k].x;
      float n1 = av[k].y * bn - an * bv[k].y, dd1 = av[k].y * bn + an * bv[k].y;
      float n2 = av[k].z * bn - an * bv[k].z, dd2 = av[k].z * bn + an * bv[k].z;
      float n3 = av[k].w * bn - an * bv[k].w, dd3 = av[k].w * bn + an * bv[k].w;
      num2 += n0 * n0 + n1 * n1 + n2 * n2 + n3 * n3;
      den2 += dd0 * dd0 + dd1 * dd1 + dd2 * dd2 + dd3 * dd3;
    }
    ang = 2.0f * atan2f(sqrtf(num2), sqrtf(den2));
  }

  // Wave sum of the 31 angles -> p_curv everywhere.
  float tot = ang;
  #pragma unroll
  for (int m = 1; m < 64; m <<= 1) tot += __shfl_xor(tot, m, 64);
  float p_curv = tot / 31.0f;

  // Outputs (flat concatenation, all as float32).
  float* out_xyz  = out;                              // 8192*3
  float* out_feat = out + (size_t)BATCH * NGROUP * 3; // 8192*33
  float* out_sw   = out_feat + (size_t)BATCH * NGROUP * (FDIM + 1);
  float* out_lab  = out_sw  + (size_t)BATCH * NGROUP;
  float* out_sif  = out_lab + (size_t)BATCH * NGROUP;

  if (lane < FDIM)  out_feat[(size_t)qid * (FDIM + 1) + lane] = my_a;
  if (lane == FDIM) out_feat[(size_t)qid * (FDIM + 1) + FDIM] = p_curv;
  if (lane == 0) {
    out_xyz[(size_t)qid * 3 + 0] = qx;
    out_xyz[(size_t)qid * 3 + 1] = qy;
    out_xyz[(size_t)qid * 3 + 2] = qz;
    out_sw[qid]  = (p_curv > 0.087266f) ? 1.0f : 0.0f;
    out_lab[qid] = (float)labels[gq];
    out_sif[qid] = (float)gq;   // s_idx + b*N
  }
}

extern "C" void kernel_launch(void* const* d_in, const int* in_sizes, int n_in,
                              void* d_out, int out_size, void* d_ws, size_t ws_size,
                              hipStream_t stream) {
  const float* coord  = (const float*)d_in[0];
  const float* feat   = (const float*)d_in[1];
  const int*   labels = (const int*)d_in[2];

  // ws layout: [2][64] u64 ping-pong slots, then [8192] int s_idx (+1
  // encoded, 0 = unpublished). Both must start zeroed.
  unsigned long long* slots = (unsigned long long*)d_ws;
  int* s_idx_ws = (int*)((char*)d_ws +
                         2 * BATCH * NBLK * sizeof(unsigned long long));
  const size_t zbytes = 2 * BATCH * NBLK * sizeof(unsigned long long)
                      + (size_t)BATCH * NGROUP * sizeof(int);

  hipMemsetAsync(d_ws, 0, zbytes, stream);
  fused_kernel<<<NFPSBLK + NKNNBLK, FTPB, 0, stream>>>(
      coord, feat, labels, slots, s_idx_ws, (float*)d_out);
}